// Round 2
// baseline (296.532 us; speedup 1.0000x reference)
//
#include <hip/hip_runtime.h>

// Squared Euclidean distance matrix: out[n][m] = sq1[n] + sq2[m] - 2*dot(x1[n],x2[m]), clamped >= 0.
// N = M = 8192, K = 64, fp32 in/out. Output 256 MB -> HBM-write-bound floor ~43us.
// Cross term via bf16 MFMA (16x16x32); norms kept fp32 exact. Error budget:
// 2*|dot_fp32 - dot_bf16| ~ O(1) << threshold.
//
// Per block: 128x128 out tile, 256 threads (4 waves), each wave a 64x64 quadrant
// = 4x4 MFMA tiles, K=64 = 2 k-steps. LDS bf16 tiles row-major, stride 72 ushort
// (+16B pad) -> fragment ds_read_b128 ~conflict-free.
//
// KEY CHANGE vs 278us version: MFMA operands are SWAPPED — we compute
// D' = X2_tile * X1_tile^T (= cross^T). A- and B-fragments of
// mfma_f32_16x16x32_bf16 have identical lane layouts (both read 8 k-elems from
// row lane&15), so the swap is free. D' layout [m89/m91]: col(lane&15) -> x1 row
// (output ROW), row((lane>>4)*4+reg) -> x2 row (output COL). Each lane therefore
// holds 4 CONSECUTIVE output columns -> dwordx4 stores, 1 KiB per wave-store
// instead of 64 scalar dword stores/thread. Stores are nontemporal: output is
// write-once, keep x1/x2 resident in per-XCD L2.
// (Round-1 fix: __builtin_nontemporal_store needs ext_vector_type, not HIP float4.)

typedef __bf16 bf16x8 __attribute__((ext_vector_type(8)));
typedef float floatx4 __attribute__((ext_vector_type(4)));
typedef unsigned short ushort8 __attribute__((ext_vector_type(8)));

#define TILE 128
#define KD 64
#define LDSS 72   // ushort per row: 64 data + 8 pad (16 B); row = 144 B, 16B-aligned

__device__ __forceinline__ unsigned short f2bf(float x) {
    // round-to-nearest-even fp32 -> bf16 (finite inputs only)
    union { float f; unsigned int u; } v; v.f = x;
    return (unsigned short)((v.u + 0x7FFFu + ((v.u >> 16) & 1u)) >> 16);
}

__global__ void sqeuclid_mfma(const float* __restrict__ x1,
                              const float* __restrict__ x2,
                              float* __restrict__ out,
                              int M) {
    __shared__ unsigned short a_s[TILE][LDSS];   // bf16 bits of x1 tile [row][k]
    __shared__ unsigned short b_s[TILE][LDSS];   // bf16 bits of x2 tile [row][k]
    __shared__ float sq1_s[TILE];
    __shared__ float sq2_s[TILE];

    const int t = threadIdx.x;                 // 0..255
    const int block_row = blockIdx.y * TILE;
    const int block_col = blockIdx.x * TILE;

    // ---- Stage fp32 -> bf16 into LDS; fp32 row norms on the side.
    // Thread t stages one full row: matrix = t>>7, local row = t&127.
    {
        const int r = t & 127;
        const float* src = (t < TILE) ? (x1 + (size_t)(block_row + r) * KD)
                                      : (x2 + (size_t)(block_col + r) * KD);
        unsigned short* dst = (t < TILE) ? a_s[r] : b_s[r];
        float nrm = 0.f;
        #pragma unroll
        for (int i = 0; i < 8; ++i) {          // 2 float4 -> 1 ushort8 (16B LDS write)
            const float4 f0 = ((const float4*)src)[2 * i];
            const float4 f1 = ((const float4*)src)[2 * i + 1];
            nrm = fmaf(f0.x, f0.x, nrm); nrm = fmaf(f0.y, f0.y, nrm);
            nrm = fmaf(f0.z, f0.z, nrm); nrm = fmaf(f0.w, f0.w, nrm);
            nrm = fmaf(f1.x, f1.x, nrm); nrm = fmaf(f1.y, f1.y, nrm);
            nrm = fmaf(f1.z, f1.z, nrm); nrm = fmaf(f1.w, f1.w, nrm);
            ushort8 pk;
            pk[0] = f2bf(f0.x); pk[1] = f2bf(f0.y); pk[2] = f2bf(f0.z); pk[3] = f2bf(f0.w);
            pk[4] = f2bf(f1.x); pk[5] = f2bf(f1.y); pk[6] = f2bf(f1.z); pk[7] = f2bf(f1.w);
            *(ushort8*)&dst[i * 8] = pk;       // bank = 4*(r+i) mod 32: even spread
        }
        if (t < TILE) sq1_s[r] = nrm; else sq2_s[r] = nrm;
    }
    __syncthreads();

    // ---- MFMA: wave quadrant (wr,wc), 4x4 tiles of 16x16, K = 2 steps of 32.
    // A-operand: rows of b_s (x2), B-operand: rows of a_s (x1) — SWAPPED.
    // acc[i][j]: i = x2 col-block, j = x1 row-block.
    // Lane mapping of acc[i][j]: output row = wr + j*16 + (lane&15),
    //                            output cols = wc + i*16 + (lane>>4)*4 + {0..3}.
    const int wave = t >> 6, lane = t & 63;
    const int wr = (wave >> 1) * 64;           // quadrant row base (x1)
    const int wc = (wave & 1) * 64;            // quadrant col base (x2)
    const int lm = lane & 15, lq = lane >> 4;

    floatx4 acc[4][4];
    #pragma unroll
    for (int i = 0; i < 4; ++i)
        #pragma unroll
        for (int j = 0; j < 4; ++j)
            acc[i][j] = (floatx4){0.f, 0.f, 0.f, 0.f};

    #pragma unroll
    for (int ks = 0; ks < 2; ++ks) {
        const int koff = ks * 32 + lq * 8;     // bf16 elements; *2 bytes, 16B-aligned
        bf16x8 afr[4], bfr[4];
        #pragma unroll
        for (int i = 0; i < 4; ++i) {
            afr[i] = *(const bf16x8*)&a_s[wr + i * 16 + lm][koff];   // x1 rows
            bfr[i] = *(const bf16x8*)&b_s[wc + i * 16 + lm][koff];   // x2 rows
        }
        #pragma unroll
        for (int i = 0; i < 4; ++i)
            #pragma unroll
            for (int j = 0; j < 4; ++j)
                acc[i][j] = __builtin_amdgcn_mfma_f32_16x16x32_bf16(
                    bfr[i], afr[j], acc[i][j], 0, 0, 0);   // D' = X2 * X1^T
    }

    // ---- Epilogue: d2 = sq1 + sq2 - 2*dot, clamp, dwordx4 nontemporal stores.
    // Per wave-store: 16 rows x 64 contiguous bytes = 1 KiB, ideal pattern.
    floatx4 s2q[4];
    #pragma unroll
    for (int i = 0; i < 4; ++i)
        s2q[i] = *(const floatx4*)&sq2_s[wc + i * 16 + lq * 4];   // broadcast per lq

    #pragma unroll
    for (int j = 0; j < 4; ++j) {
        const int lrow = wr + j * 16 + lm;
        const float s1 = sq1_s[lrow];
        const size_t gbase = (size_t)(block_row + lrow) * M + block_col;
        #pragma unroll
        for (int i = 0; i < 4; ++i) {
            const int lcol = wc + i * 16 + lq * 4;
            floatx4 v;
            #pragma unroll
            for (int r = 0; r < 4; ++r)
                v[r] = fmaxf(fmaf(-2.f, acc[i][j][r], s1 + s2q[i][r]), 0.f);
            __builtin_nontemporal_store(v, (floatx4*)(out + gbase + lcol));
        }
    }
}

extern "C" void kernel_launch(void* const* d_in, const int* in_sizes, int n_in,
                              void* d_out, int out_size, void* d_ws, size_t ws_size,
                              hipStream_t stream) {
    const float* x1 = (const float*)d_in[0];
    const float* x2 = (const float*)d_in[1];
    float* out = (float*)d_out;
    const int N = in_sizes[0] / KD;   // 8192
    const int M = in_sizes[1] / KD;   // 8192

    dim3 grid(M / TILE, N / TILE);    // (64, 64)
    dim3 block(256);
    sqeuclid_mfma<<<grid, block, 0, stream>>>(x1, x2, out, M);
}

// Round 4
// 272.989 us; speedup vs baseline: 1.0862x; 1.0862x over previous
//
#include <hip/hip_runtime.h>

// Squared Euclidean distance matrix: out[n][m] = sq1[n] + sq2[m] - 2*dot(x1[n],x2[m]), clamped >= 0.
// N = M = 8192, K = 64, fp32 in/out. Output 256 MB -> HBM-write-bound floor ~43us.
//
// Two-kernel design:
//   1) convert_rows prepass (one thread/row): fp32 -> bf16 into d_ws ONCE,
//      fp32 row norms on the side. Kills the 64x-redundant per-block conversion
//      (~250 VALU/thread) the old single-kernel version paid.
//   2) sqeuclid_main: NO LDS, NO __syncthreads. MFMA fragments are loaded
//      directly from the global bf16 arrays (2 MB total -> fully L2-resident
//      per XCD). Fragment load = 16 rows x 64 B dense, L2-friendly.
//      Per thread: 16 frag loads -> 32 MFMA -> 8 norm loads -> 16 dwordx4 stores.
//      Occupancy no longer LDS-bound (was 4 blocks/CU at 37 KB LDS).
//
// MFMA operand order SWAPPED (D' = X2*X1^T): A/B fragments of
// mfma_f32_16x16x32_bf16 have identical lane layouts so the swap is free, and
// D' gives each lane 4 CONSECUTIVE output columns -> dwordx4 stores
// (1 KiB per wave-store). Plain cached stores (nt regressed in round 2).
//
// acc[i][j] lane mapping: output row = wr + j*16 + (lane&15),
//                         output cols = wc + i*16 + (lane>>4)*4 + {0..3}.
//
// (Round 3 bench was an infra failure — container acquisition — not a kernel
//  failure; this is the same design resubmitted.)

typedef __bf16 bf16x8 __attribute__((ext_vector_type(8)));
typedef float floatx4 __attribute__((ext_vector_type(4)));
typedef unsigned short ushort8 __attribute__((ext_vector_type(8)));

#define TILE 128
#define KD 64
#define LDSS 72

__device__ __forceinline__ unsigned short f2bf(float x) {
    // round-to-nearest-even fp32 -> bf16 (finite inputs only)
    union { float f; unsigned int u; } v; v.f = x;
    return (unsigned short)((v.u + 0x7FFFu + ((v.u >> 16) & 1u)) >> 16);
}

// ---------------- prepass: fp32 rows -> bf16 rows + fp32 norms ----------------
__global__ __launch_bounds__(256) void convert_rows(
        const float* __restrict__ x1,
        const float* __restrict__ x2,
        unsigned short* __restrict__ xb1,
        unsigned short* __restrict__ xb2,
        float* __restrict__ sq1,
        float* __restrict__ sq2,
        int N, int M) {
    const int tid = blockIdx.x * blockDim.x + threadIdx.x;
    if (tid >= N + M) return;
    const int r = (tid < N) ? tid : tid - N;
    const float* src = (tid < N) ? (x1 + (size_t)r * KD) : (x2 + (size_t)r * KD);
    unsigned short* dst = (tid < N) ? (xb1 + (size_t)r * KD) : (xb2 + (size_t)r * KD);
    float nrm = 0.f;
    #pragma unroll
    for (int i = 0; i < 8; ++i) {
        const float4 f0 = ((const float4*)src)[2 * i];
        const float4 f1 = ((const float4*)src)[2 * i + 1];
        nrm = fmaf(f0.x, f0.x, nrm); nrm = fmaf(f0.y, f0.y, nrm);
        nrm = fmaf(f0.z, f0.z, nrm); nrm = fmaf(f0.w, f0.w, nrm);
        nrm = fmaf(f1.x, f1.x, nrm); nrm = fmaf(f1.y, f1.y, nrm);
        nrm = fmaf(f1.z, f1.z, nrm); nrm = fmaf(f1.w, f1.w, nrm);
        ushort8 pk;
        pk[0] = f2bf(f0.x); pk[1] = f2bf(f0.y); pk[2] = f2bf(f0.z); pk[3] = f2bf(f0.w);
        pk[4] = f2bf(f1.x); pk[5] = f2bf(f1.y); pk[6] = f2bf(f1.z); pk[7] = f2bf(f1.w);
        *(ushort8*)&dst[i * 8] = pk;
    }
    if (tid < N) sq1[r] = nrm; else sq2[r] = nrm;
}

// ---------------- main: LDS-free MFMA + fused epilogue ----------------
__global__ __launch_bounds__(256) void sqeuclid_main(
        const unsigned short* __restrict__ xb1,
        const unsigned short* __restrict__ xb2,
        const float* __restrict__ sq1,
        const float* __restrict__ sq2,
        float* __restrict__ out, int M) {
    const int t = threadIdx.x;
    const int block_row = blockIdx.y * TILE;
    const int block_col = blockIdx.x * TILE;
    const int wave = t >> 6, lane = t & 63;
    const int wr = (wave >> 1) * 64;           // quadrant row base (x1)
    const int wc = (wave & 1) * 64;            // quadrant col base (x2)
    const int lm = lane & 15, lq = lane >> 4;

    const int arow = block_row + wr + lm;      // x1 fragment base row (+ j*16)
    const int brow = block_col + wc + lm;      // x2 fragment base row (+ i*16)

    floatx4 acc[4][4];
    #pragma unroll
    for (int i = 0; i < 4; ++i)
        #pragma unroll
        for (int j = 0; j < 4; ++j)
            acc[i][j] = (floatx4){0.f, 0.f, 0.f, 0.f};

    #pragma unroll
    for (int ks = 0; ks < 2; ++ks) {
        const int koff = ks * 32 + lq * 8;     // bf16 elems; 16B-aligned bytes
        bf16x8 afr[4], bfr[4];
        #pragma unroll
        for (int i = 0; i < 4; ++i) {
            afr[i] = *(const bf16x8*)&xb1[(size_t)(arow + i * 16) * KD + koff];
            bfr[i] = *(const bf16x8*)&xb2[(size_t)(brow + i * 16) * KD + koff];
        }
        #pragma unroll
        for (int i = 0; i < 4; ++i)
            #pragma unroll
            for (int j = 0; j < 4; ++j)
                acc[i][j] = __builtin_amdgcn_mfma_f32_16x16x32_bf16(
                    bfr[i], afr[j], acc[i][j], 0, 0, 0);   // D' = X2 * X1^T
    }

    floatx4 s2q[4];
    #pragma unroll
    for (int i = 0; i < 4; ++i)
        s2q[i] = *(const floatx4*)&sq2[block_col + wc + i * 16 + lq * 4];

    #pragma unroll
    for (int j = 0; j < 4; ++j) {
        const int lrow = wr + j * 16 + lm;
        const float s1 = sq1[block_row + lrow];
        const size_t gbase = (size_t)(block_row + lrow) * M + block_col;
        #pragma unroll
        for (int i = 0; i < 4; ++i) {
            floatx4 v;
            #pragma unroll
            for (int r = 0; r < 4; ++r)
                v[r] = fmaxf(fmaf(-2.f, acc[i][j][r], s1 + s2q[i][r]), 0.f);
            *(floatx4*)(out + gbase + wc + i * 16 + lq * 4) = v;
        }
    }
}

// ---------------- fallback: single-kernel LDS version (no workspace) ----------------
__global__ void sqeuclid_fused(const float* __restrict__ x1,
                               const float* __restrict__ x2,
                               float* __restrict__ out, int M) {
    __shared__ unsigned short a_s[TILE][LDSS];
    __shared__ unsigned short b_s[TILE][LDSS];
    __shared__ float sq1_s[TILE];
    __shared__ float sq2_s[TILE];

    const int t = threadIdx.x;
    const int block_row = blockIdx.y * TILE;
    const int block_col = blockIdx.x * TILE;
    {
        const int r = t & 127;
        const float* src = (t < TILE) ? (x1 + (size_t)(block_row + r) * KD)
                                      : (x2 + (size_t)(block_col + r) * KD);
        unsigned short* dst = (t < TILE) ? a_s[r] : b_s[r];
        float nrm = 0.f;
        #pragma unroll
        for (int i = 0; i < 8; ++i) {
            const float4 f0 = ((const float4*)src)[2 * i];
            const float4 f1 = ((const float4*)src)[2 * i + 1];
            nrm = fmaf(f0.x, f0.x, nrm); nrm = fmaf(f0.y, f0.y, nrm);
            nrm = fmaf(f0.z, f0.z, nrm); nrm = fmaf(f0.w, f0.w, nrm);
            nrm = fmaf(f1.x, f1.x, nrm); nrm = fmaf(f1.y, f1.y, nrm);
            nrm = fmaf(f1.z, f1.z, nrm); nrm = fmaf(f1.w, f1.w, nrm);
            ushort8 pk;
            pk[0] = f2bf(f0.x); pk[1] = f2bf(f0.y); pk[2] = f2bf(f0.z); pk[3] = f2bf(f0.w);
            pk[4] = f2bf(f1.x); pk[5] = f2bf(f1.y); pk[6] = f2bf(f1.z); pk[7] = f2bf(f1.w);
            *(ushort8*)&dst[i * 8] = pk;
        }
        if (t < TILE) sq1_s[r] = nrm; else sq2_s[r] = nrm;
    }
    __syncthreads();

    const int wave = t >> 6, lane = t & 63;
    const int wr = (wave >> 1) * 64;
    const int wc = (wave & 1) * 64;
    const int lm = lane & 15, lq = lane >> 4;

    floatx4 acc[4][4];
    #pragma unroll
    for (int i = 0; i < 4; ++i)
        #pragma unroll
        for (int j = 0; j < 4; ++j)
            acc[i][j] = (floatx4){0.f, 0.f, 0.f, 0.f};

    #pragma unroll
    for (int ks = 0; ks < 2; ++ks) {
        const int koff = ks * 32 + lq * 8;
        bf16x8 afr[4], bfr[4];
        #pragma unroll
        for (int i = 0; i < 4; ++i) {
            afr[i] = *(const bf16x8*)&a_s[wr + i * 16 + lm][koff];
            bfr[i] = *(const bf16x8*)&b_s[wc + i * 16 + lm][koff];
        }
        #pragma unroll
        for (int i = 0; i < 4; ++i)
            #pragma unroll
            for (int j = 0; j < 4; ++j)
                acc[i][j] = __builtin_amdgcn_mfma_f32_16x16x32_bf16(
                    bfr[i], afr[j], acc[i][j], 0, 0, 0);
    }

    floatx4 s2q[4];
    #pragma unroll
    for (int i = 0; i < 4; ++i)
        s2q[i] = *(const floatx4*)&sq2_s[wc + i * 16 + lq * 4];

    #pragma unroll
    for (int j = 0; j < 4; ++j) {
        const int lrow = wr + j * 16 + lm;
        const float s1 = sq1_s[lrow];
        const size_t gbase = (size_t)(block_row + lrow) * M + block_col;
        #pragma unroll
        for (int i = 0; i < 4; ++i) {
            floatx4 v;
            #pragma unroll
            for (int r = 0; r < 4; ++r)
                v[r] = fmaxf(fmaf(-2.f, acc[i][j][r], s1 + s2q[i][r]), 0.f);
            *(floatx4*)(out + gbase + wc + i * 16 + lq * 4) = v;
        }
    }
}

extern "C" void kernel_launch(void* const* d_in, const int* in_sizes, int n_in,
                              void* d_out, int out_size, void* d_ws, size_t ws_size,
                              hipStream_t stream) {
    const float* x1 = (const float*)d_in[0];
    const float* x2 = (const float*)d_in[1];
    float* out = (float*)d_out;
    const int N = in_sizes[0] / KD;   // 8192
    const int M = in_sizes[1] / KD;   // 8192

    dim3 grid(M / TILE, N / TILE);    // (64, 64)
    dim3 block(256);

    const size_t xb1_off = 0;
    const size_t xb2_off = (size_t)N * KD * 2;
    const size_t sq1_off = xb2_off + (size_t)M * KD * 2;
    const size_t sq2_off = sq1_off + (size_t)N * 4;
    const size_t ws_needed = sq2_off + (size_t)M * 4;

    if (d_ws != nullptr && ws_size >= ws_needed) {
        unsigned short* xb1 = (unsigned short*)((char*)d_ws + xb1_off);
        unsigned short* xb2 = (unsigned short*)((char*)d_ws + xb2_off);
        float* sq1 = (float*)((char*)d_ws + sq1_off);
        float* sq2 = (float*)((char*)d_ws + sq2_off);
        const int rows = N + M;
        convert_rows<<<dim3((rows + 255) / 256), dim3(256), 0, stream>>>(
            x1, x2, xb1, xb2, sq1, sq2, N, M);
        sqeuclid_main<<<grid, block, 0, stream>>>(xb1, xb2, sq1, sq2, out, M);
    } else {
        sqeuclid_fused<<<grid, block, 0, stream>>>(x1, x2, out, M);
    }
}